// Round 11
// baseline (126.067 us; speedup 1.0000x reference)
//
#include <hip/hip_runtime.h>
#include <hip/hip_bf16.h>

#define BB 16
#define NN 1024
#define DIN 64
#define KK 8
#define DP 64

typedef __bf16 bf16x8 __attribute__((ext_vector_type(8)));
typedef float f32x16 __attribute__((ext_vector_type(16)));

// ws layout: z bf16 [K][B*N][DP]  = 16 MiB at offset 0
//            Wt bf16 [K][DP][DIN] = 64 KiB at offset 16 MiB
#define Z_BYTES (16777216UL)

// Fused LDS-only barrier: waits DS ops, does NOT drain global stores
#define LDS_BARRIER() asm volatile("s_waitcnt lgkmcnt(0)\n\ts_barrier" ::: "memory")

// ---------------------------------------------------------------------------
// Kernel 0: Wt[k][e][d] = bf16(W[k][d][e])   (8 blocks, one per k)
// ---------------------------------------------------------------------------
__global__ __launch_bounds__(256) void wt_kernel(const float* __restrict__ W,
                                                 __hip_bfloat16* __restrict__ Wt)
{
    __shared__ float Wl[DIN * DP];
    const int k = blockIdx.x;
    const int tid = threadIdx.x;

    const float4* src = (const float4*)(W + (size_t)k * DIN * DP);
    float4* dst = (float4*)Wl;
    #pragma unroll
    for (int i = 0; i < 4; ++i) dst[tid + i * 256] = src[tid + i * 256];
    __syncthreads();

    const int e  = tid >> 2;          // 0..63
    const int dc = (tid & 3) * 16;    // d-chunk
    __hip_bfloat16 v[16];
    #pragma unroll
    for (int i = 0; i < 16; ++i)
        v[i] = __float2bfloat16(Wl[(dc + i) * DP + e]);
    *(uint4*)(Wt + ((size_t)k * DP + e) * DIN + dc)     = *(uint4*)&v[0];
    *(uint4*)(Wt + ((size_t)k * DP + e) * DIN + dc + 8) = *(uint4*)&v[8];
}

// ---------------------------------------------------------------------------
// Kernel 1: enc, 8-WAVE edition (512 thr): wave w computes attribute k=w for
// this block's 32 rows. Same validated fragment/store mappings as r2-r10
// (a-loop collapsed, k = wid). Half VGPR/wave, 16 waves/CU (was 8).
// ---------------------------------------------------------------------------
__global__ __launch_bounds__(512) void enc_kernel(const float* __restrict__ x,
                                                  const __hip_bfloat16* __restrict__ Wt,
                                                  const float* __restrict__ bias,
                                                  __hip_bfloat16* __restrict__ z)
{
    const int tid  = threadIdx.x;
    const int lane = tid & 63;
    const int k    = tid >> 6;        // wave id == attribute
    const int l31  = lane & 31;
    const int h    = lane >> 5;
    const int row0 = blockIdx.x * 32;
    const int row  = row0 + l31;

    bf16x8 xb[4];
    #pragma unroll
    for (int kk = 0; kk < 4; ++kk) {
        const float* xp = x + (size_t)row * DIN + kk * 16 + h * 8;
        float4 lo = *(const float4*)xp;
        float4 hi = *(const float4*)(xp + 4);
        bf16x8 t;
        t[0] = (__bf16)lo.x; t[1] = (__bf16)lo.y; t[2] = (__bf16)lo.z; t[3] = (__bf16)lo.w;
        t[4] = (__bf16)hi.x; t[5] = (__bf16)hi.y; t[6] = (__bf16)hi.z; t[7] = (__bf16)hi.w;
        xb[kk] = t;
    }

    #pragma unroll
    for (int et = 0; et < 2; ++et) {
        f32x16 acc;
        #pragma unroll
        for (int i = 0; i < 16; ++i) acc[i] = 0.0f;
        const __hip_bfloat16* wp =
            Wt + ((size_t)k * DP + et * 32 + l31) * DIN + h * 8;
        #pragma unroll
        for (int kk = 0; kk < 4; ++kk) {
            bf16x8 wf = *(const bf16x8*)(wp + kk * 16);
            acc = __builtin_amdgcn_mfma_f32_32x32x16_bf16(wf, xb[kk], acc, 0, 0, 0);
        }
        #pragma unroll
        for (int g = 0; g < 4; ++g) {
            const int e0 = et * 32 + 8 * g + 4 * h;
            float4 b4 = *(const float4*)(bias + k * DP + e0);
            union { __hip_bfloat16 b[4]; uint2 u; } pk;
            pk.b[0] = __float2bfloat16(fmaxf(acc[g * 4 + 0] + b4.x, 0.0f));
            pk.b[1] = __float2bfloat16(fmaxf(acc[g * 4 + 1] + b4.y, 0.0f));
            pk.b[2] = __float2bfloat16(fmaxf(acc[g * 4 + 2] + b4.z, 0.0f));
            pk.b[3] = __float2bfloat16(fmaxf(acc[g * 4 + 3] + b4.w, 0.0f));
            *(uint2*)(z + ((size_t)k * BB * NN + row) * DP + e0) = pk.u;
        }
    }
}

// ---------------------------------------------------------------------------
// Kernel 2: gram — byte-identical to r8/r10's best-measured structure
// (single 36KB buffer, 8 waves/attr, 32 waves/CU, JIT B-loads, LDS-only
// barriers). Measured pattern-roofline candidate: ~109us for 537MB writes
// + 590MB L2 reads.
// ---------------------------------------------------------------------------
__global__ __launch_bounds__(512, 8) void gram_kernel(const __hip_bfloat16* __restrict__ z,
                                                      float* __restrict__ out)
{
    __shared__ float tile[32 * 32 * 9];   // 36 KB

    const int bid = blockIdx.x;
    const int b   = bid & 15;
    const int nt  = (bid >> 4) & 31;
    const int mh  = bid >> 9;             // 0..3
    const int tid  = threadIdx.x;
    const int lane = tid & 63;
    const int k    = tid >> 6;            // wave id == attribute
    const int rrow = lane & 31;
    const int h    = lane >> 5;

    const size_t rowbase = ((size_t)k * BB + b) * NN;   // this attr's slice

    bf16x8 a0[4];
    {
        const size_t baseA = (rowbase + nt * 32 + rrow) * DP + h * 8;
        #pragma unroll
        for (int kk = 0; kk < 4; ++kk)
            a0[kk] = *(const bf16x8*)(z + baseA + kk * 16);
    }

    #pragma unroll 1
    for (int it = 0; it < 8; ++it) {
        const int mt = mh * 8 + it;

        const size_t baseB = (rowbase + (size_t)mt * 32 + rrow) * DP + h * 8;
        bf16x8 b0[4];
        #pragma unroll
        for (int kk = 0; kk < 4; ++kk)
            b0[kk] = *(const bf16x8*)(z + baseB + kk * 16);

        f32x16 acc;
        #pragma unroll
        for (int i = 0; i < 16; ++i) acc[i] = 0.0f;
        #pragma unroll
        for (int kk = 0; kk < 4; ++kk)
            acc = __builtin_amdgcn_mfma_f32_32x32x16_bf16(a0[kk], b0[kk], acc, 0, 0, 0);

        #pragma unroll
        for (int r = 0; r < 16; ++r) {
            int n = (r & 3) + 8 * (r >> 2) + 4 * h;
            tile[(n * 32 + rrow) * 9 + k] = acc[r];
        }

        LDS_BARRIER();

        float* op = out + (((size_t)b * NN + nt * 32) * NN + (size_t)mt * 32) * KK;
        #pragma unroll
        for (int j = 0; j < 4; ++j) {
            int flat = j * 512 + tid;
            int n  = flat >> 6;
            int c4 = flat & 63;
            int m  = c4 >> 1;
            int kq = (c4 & 1) * 4;
            int off = (n * 32 + m) * 9 + kq;
            float4 v = make_float4(tile[off], tile[off + 1], tile[off + 2], tile[off + 3]);
            *(float4*)(op + (size_t)n * NN * KK + c4 * 4) = v;
        }

        LDS_BARRIER();
    }
}

// ---------------------------------------------------------------------------
extern "C" void kernel_launch(void* const* d_in, const int* in_sizes, int n_in,
                              void* d_out, int out_size, void* d_ws, size_t ws_size,
                              hipStream_t stream)
{
    const float* x    = (const float*)d_in[0];
    const float* W    = (const float*)d_in[1];
    const float* bias = (const float*)d_in[2];
    float* out        = (float*)d_out;
    __hip_bfloat16* z  = (__hip_bfloat16*)d_ws;
    __hip_bfloat16* Wt = (__hip_bfloat16*)((char*)d_ws + Z_BYTES);

    wt_kernel <<<dim3(KK),           dim3(256), 0, stream>>>(W, Wt);
    enc_kernel<<<dim3(BB * NN / 32), dim3(512), 0, stream>>>(x, Wt, bias, z);
    gram_kernel<<<dim3(16 * 32 * 4), dim3(512), 0, stream>>>(z, out);
}

// Round 13
// 122.932 us; speedup vs baseline: 1.0255x; 1.0255x over previous
//
#include <hip/hip_runtime.h>
#include <hip/hip_bf16.h>

#define BB 16
#define NN 1024
#define DIN 64
#define KK 8
#define DP 64

typedef __bf16 bf16x8 __attribute__((ext_vector_type(8)));
typedef float f32x4 __attribute__((ext_vector_type(4)));
typedef float f32x16 __attribute__((ext_vector_type(16)));

// ws layout: z bf16 [K][B*N][DP]  = 16 MiB at offset 0
//            Wt bf16 [K][DP][DIN] = 64 KiB at offset 16 MiB
#define Z_BYTES (16777216UL)

// Fused LDS-only barrier: waits DS ops, does NOT drain global stores
#define LDS_BARRIER() asm volatile("s_waitcnt lgkmcnt(0)\n\ts_barrier" ::: "memory")

// ---------------------------------------------------------------------------
// Kernel 0: Wt[k][e][d] = bf16(W[k][d][e])   (8 blocks, one per k)
// ---------------------------------------------------------------------------
__global__ __launch_bounds__(256) void wt_kernel(const float* __restrict__ W,
                                                 __hip_bfloat16* __restrict__ Wt)
{
    __shared__ float Wl[DIN * DP];
    const int k = blockIdx.x;
    const int tid = threadIdx.x;

    const float4* src = (const float4*)(W + (size_t)k * DIN * DP);
    float4* dst = (float4*)Wl;
    #pragma unroll
    for (int i = 0; i < 4; ++i) dst[tid + i * 256] = src[tid + i * 256];
    __syncthreads();

    const int e  = tid >> 2;          // 0..63
    const int dc = (tid & 3) * 16;    // d-chunk
    __hip_bfloat16 v[16];
    #pragma unroll
    for (int i = 0; i < 16; ++i)
        v[i] = __float2bfloat16(Wl[(dc + i) * DP + e]);
    *(uint4*)(Wt + ((size_t)k * DP + e) * DIN + dc)     = *(uint4*)&v[0];
    *(uint4*)(Wt + ((size_t)k * DP + e) * DIN + dc + 8) = *(uint4*)&v[8];
}

// ---------------------------------------------------------------------------
// Kernel 1: enc, 8-wave edition (512 thr, wave = attribute) — validated r11.
// ---------------------------------------------------------------------------
__global__ __launch_bounds__(512) void enc_kernel(const float* __restrict__ x,
                                                  const __hip_bfloat16* __restrict__ Wt,
                                                  const float* __restrict__ bias,
                                                  __hip_bfloat16* __restrict__ z)
{
    const int tid  = threadIdx.x;
    const int lane = tid & 63;
    const int k    = tid >> 6;        // wave id == attribute
    const int l31  = lane & 31;
    const int h    = lane >> 5;
    const int row0 = blockIdx.x * 32;
    const int row  = row0 + l31;

    bf16x8 xb[4];
    #pragma unroll
    for (int kk = 0; kk < 4; ++kk) {
        const float* xp = x + (size_t)row * DIN + kk * 16 + h * 8;
        float4 lo = *(const float4*)xp;
        float4 hi = *(const float4*)(xp + 4);
        bf16x8 t;
        t[0] = (__bf16)lo.x; t[1] = (__bf16)lo.y; t[2] = (__bf16)lo.z; t[3] = (__bf16)lo.w;
        t[4] = (__bf16)hi.x; t[5] = (__bf16)hi.y; t[6] = (__bf16)hi.z; t[7] = (__bf16)hi.w;
        xb[kk] = t;
    }

    #pragma unroll
    for (int et = 0; et < 2; ++et) {
        f32x16 acc;
        #pragma unroll
        for (int i = 0; i < 16; ++i) acc[i] = 0.0f;
        const __hip_bfloat16* wp =
            Wt + ((size_t)k * DP + et * 32 + l31) * DIN + h * 8;
        #pragma unroll
        for (int kk = 0; kk < 4; ++kk) {
            bf16x8 wf = *(const bf16x8*)(wp + kk * 16);
            acc = __builtin_amdgcn_mfma_f32_32x32x16_bf16(wf, xb[kk], acc, 0, 0, 0);
        }
        #pragma unroll
        for (int g = 0; g < 4; ++g) {
            const int e0 = et * 32 + 8 * g + 4 * h;
            float4 b4 = *(const float4*)(bias + k * DP + e0);
            union { __hip_bfloat16 b[4]; uint2 u; } pk;
            pk.b[0] = __float2bfloat16(fmaxf(acc[g * 4 + 0] + b4.x, 0.0f));
            pk.b[1] = __float2bfloat16(fmaxf(acc[g * 4 + 1] + b4.y, 0.0f));
            pk.b[2] = __float2bfloat16(fmaxf(acc[g * 4 + 2] + b4.z, 0.0f));
            pk.b[3] = __float2bfloat16(fmaxf(acc[g * 4 + 3] + b4.w, 0.0f));
            *(uint2*)(z + ((size_t)k * BB * NN + row) * DP + e0) = pk.u;
        }
    }
}

// ---------------------------------------------------------------------------
// Kernel 2: gram — r8/r10 structure EXACTLY, one change: output stores are
// NONTEMPORAL (no L2 write-allocate), via ext-vector f32x4 (clang builtin
// rejects HIP_vector_type). Theory: 537MB write stream thrashes the
// ~2MB/XCD z working set out of L2; nt-stores stream past L2 -> z resident.
// ---------------------------------------------------------------------------
__global__ __launch_bounds__(512, 8) void gram_kernel(const __hip_bfloat16* __restrict__ z,
                                                      float* __restrict__ out)
{
    __shared__ float tile[32 * 32 * 9];   // 36 KB

    const int bid = blockIdx.x;
    const int b   = bid & 15;
    const int nt  = (bid >> 4) & 31;
    const int mh  = bid >> 9;             // 0..3
    const int tid  = threadIdx.x;
    const int lane = tid & 63;
    const int k    = tid >> 6;            // wave id == attribute
    const int rrow = lane & 31;
    const int h    = lane >> 5;

    const size_t rowbase = ((size_t)k * BB + b) * NN;   // this attr's slice

    bf16x8 a0[4];
    {
        const size_t baseA = (rowbase + nt * 32 + rrow) * DP + h * 8;
        #pragma unroll
        for (int kk = 0; kk < 4; ++kk)
            a0[kk] = *(const bf16x8*)(z + baseA + kk * 16);
    }

    #pragma unroll 1
    for (int it = 0; it < 8; ++it) {
        const int mt = mh * 8 + it;

        const size_t baseB = (rowbase + (size_t)mt * 32 + rrow) * DP + h * 8;
        bf16x8 b0[4];
        #pragma unroll
        for (int kk = 0; kk < 4; ++kk)
            b0[kk] = *(const bf16x8*)(z + baseB + kk * 16);

        f32x16 acc;
        #pragma unroll
        for (int i = 0; i < 16; ++i) acc[i] = 0.0f;
        #pragma unroll
        for (int kk = 0; kk < 4; ++kk)
            acc = __builtin_amdgcn_mfma_f32_32x32x16_bf16(a0[kk], b0[kk], acc, 0, 0, 0);

        #pragma unroll
        for (int r = 0; r < 16; ++r) {
            int n = (r & 3) + 8 * (r >> 2) + 4 * h;
            tile[(n * 32 + rrow) * 9 + k] = acc[r];
        }

        LDS_BARRIER();

        float* op = out + (((size_t)b * NN + nt * 32) * NN + (size_t)mt * 32) * KK;
        #pragma unroll
        for (int j = 0; j < 4; ++j) {
            int flat = j * 512 + tid;
            int n  = flat >> 6;
            int c4 = flat & 63;
            int m  = c4 >> 1;
            int kq = (c4 & 1) * 4;
            int off = (n * 32 + m) * 9 + kq;
            f32x4 v = { tile[off], tile[off + 1], tile[off + 2], tile[off + 3] };
            __builtin_nontemporal_store(v, (f32x4*)(op + (size_t)n * NN * KK + c4 * 4));
        }

        LDS_BARRIER();
    }
}

// ---------------------------------------------------------------------------
extern "C" void kernel_launch(void* const* d_in, const int* in_sizes, int n_in,
                              void* d_out, int out_size, void* d_ws, size_t ws_size,
                              hipStream_t stream)
{
    const float* x    = (const float*)d_in[0];
    const float* W    = (const float*)d_in[1];
    const float* bias = (const float*)d_in[2];
    float* out        = (float*)d_out;
    __hip_bfloat16* z  = (__hip_bfloat16*)d_ws;
    __hip_bfloat16* Wt = (__hip_bfloat16*)((char*)d_ws + Z_BYTES);

    wt_kernel <<<dim3(KK),           dim3(256), 0, stream>>>(W, Wt);
    enc_kernel<<<dim3(BB * NN / 32), dim3(512), 0, stream>>>(x, Wt, bias, z);
    gram_kernel<<<dim3(16 * 32 * 4), dim3(512), 0, stream>>>(z, out);
}